// Round 1
// baseline (67.461 us; speedup 1.0000x reference)
//
#include <hip/hip_runtime.h>
#include <math.h>

// Problem constants (match reference file)
#define B_ 64
#define K_ 16
#define N_ 65536
#define D_ 256
#define H_ 64

#define N4_ (N_ / 4)          // 16384 float4 columns per (b,k) row
#define CHUNKS_ 32            // blocks per batch element
#define TPB_ 256
#define COLS_ (N4_ / CHUNKS_) // 512 float4-cols per block
#define ITERS_ (COLS_ / TPB_) // 2 iterations per thread

// ws layout: [0 .. B*K)           = total_attn accumulators
//            [B*K .. 2*B*K)       = winning_attn accumulators
// 2048 floats = 8 KB

__global__ __launch_bounds__(256) void zero_ws_kernel(float* __restrict__ ws) {
    ws[blockIdx.x * 256 + threadIdx.x] = 0.0f;   // grid = 8 blocks -> 2048 floats
}

__global__ __launch_bounds__(TPB_) void attn_stats_kernel(const float* __restrict__ attn,
                                                          float* __restrict__ ws) {
    const int b = blockIdx.x / CHUNKS_;
    const int chunk = blockIdx.x % CHUNKS_;
    const float4* base = reinterpret_cast<const float4*>(attn) + (size_t)b * K_ * N4_;

    float tot[K_], win[K_];
#pragma unroll
    for (int k = 0; k < K_; ++k) { tot[k] = 0.0f; win[k] = 0.0f; }

#pragma unroll
    for (int it = 0; it < ITERS_; ++it) {
        const int c = chunk * COLS_ + it * TPB_ + threadIdx.x;
        // k = 0 initializes the running argmax
        float4 f = base[c];
        float m0 = f.x, m1 = f.y, m2 = f.z, m3 = f.w;
        int i0 = 0, i1 = 0, i2 = 0, i3 = 0;
        tot[0] += (f.x + f.y) + (f.z + f.w);
#pragma unroll
        for (int k = 1; k < K_; ++k) {
            f = base[(size_t)k * N4_ + c];
            tot[k] += (f.x + f.y) + (f.z + f.w);
            // strict > keeps the FIRST max, matching jnp.argmax tie-break
            if (f.x > m0) { m0 = f.x; i0 = k; }
            if (f.y > m1) { m1 = f.y; i1 = k; }
            if (f.z > m2) { m2 = f.z; i2 = k; }
            if (f.w > m3) { m3 = f.w; i3 = k; }
        }
        // winner's value IS the column max -> scatter with static indexing
        // (runtime-indexed VGPR arrays would spill to scratch)
#pragma unroll
        for (int k = 0; k < K_; ++k) {
            win[k] += ((i0 == k) ? m0 : 0.0f) + ((i1 == k) ? m1 : 0.0f) +
                      ((i2 == k) ? m2 : 0.0f) + ((i3 == k) ? m3 : 0.0f);
        }
    }

    // intra-wave butterfly reduction (wave = 64 lanes on CDNA)
#pragma unroll
    for (int k = 0; k < K_; ++k) {
        float t = tot[k], w = win[k];
#pragma unroll
        for (int s = 1; s < 64; s <<= 1) {
            t += __shfl_xor(t, s, 64);
            w += __shfl_xor(w, s, 64);
        }
        tot[k] = t; win[k] = w;
    }

    // cross-wave reduction via LDS, then one atomicAdd per (b,k) per block
    __shared__ float s_tot[4][K_];
    __shared__ float s_win[4][K_];
    const int lane = threadIdx.x & 63;
    const int wv = threadIdx.x >> 6;
    if (lane == 0) {
#pragma unroll
        for (int k = 0; k < K_; ++k) { s_tot[wv][k] = tot[k]; s_win[wv][k] = win[k]; }
    }
    __syncthreads();
    if (threadIdx.x < K_) {
        const int k = threadIdx.x;
        const float t = s_tot[0][k] + s_tot[1][k] + s_tot[2][k] + s_tot[3][k];
        const float w = s_win[0][k] + s_win[1][k] + s_win[2][k] + s_win[3][k];
        atomicAdd(&ws[b * K_ + k], t);
        atomicAdd(&ws[B_ * K_ + b * K_ + k], w);
    }
}

// One 64-thread block per (b,k): tiny MLP + final combine.
__global__ __launch_bounds__(64) void finalize_kernel(const float* __restrict__ slots,
                                                      const float* __restrict__ conf,
                                                      const float* __restrict__ W1,
                                                      const float* __restrict__ b1,
                                                      const float* __restrict__ W2,
                                                      const float* __restrict__ b2,
                                                      const float* __restrict__ ws,
                                                      float* __restrict__ out) {
    const int bk = blockIdx.x;       // 0 .. B*K-1
    const int j = threadIdx.x;       // 0 .. 63 (hidden unit)

    __shared__ float s_slot[D_];
    // stage the slot row: 64 threads x float4 = 256 floats
    reinterpret_cast<float4*>(s_slot)[j] =
        reinterpret_cast<const float4*>(slots + (size_t)bk * D_)[j];
    __syncthreads();

    float acc = b1[j];
#pragma unroll 8
    for (int d = 0; d < D_; ++d) {
        acc = fmaf(s_slot[d], W1[d * H_ + j], acc);   // W1 column read coalesced over j
    }
    const float h = fmaxf(acc, 0.0f);                 // ReLU (dropout = identity at eval)
    float val = h * W2[j];
#pragma unroll
    for (int s = 1; s < 64; s <<= 1) val += __shfl_xor(val, s, 64);

    if (j == 0) {
        const float lq = 1.0f / (1.0f + expf(-(val + b2[0])));   // sigmoid
        const float t = ws[bk];
        const float w = ws[B_ * K_ + bk];
        const float aq = w / (t + 1e-8f);
        const float q = 0.4f * aq + 0.4f * lq;
        out[bk] = q * 0.2f + conf[bk] * 0.8f;
    }
}

extern "C" void kernel_launch(void* const* d_in, const int* in_sizes, int n_in,
                              void* d_out, int out_size, void* d_ws, size_t ws_size,
                              hipStream_t stream) {
    const float* slots = (const float*)d_in[0];   // [B,K,D]
    const float* attn  = (const float*)d_in[1];   // [B,K,N]
    const float* conf  = (const float*)d_in[2];   // [B,K]
    const float* W1    = (const float*)d_in[3];   // [D,H]
    const float* b1    = (const float*)d_in[4];   // [H]
    const float* W2    = (const float*)d_in[5];   // [H,1]
    const float* b2    = (const float*)d_in[6];   // [1]
    float* out = (float*)d_out;                   // [B,K]
    float* ws  = (float*)d_ws;

    // harness poisons d_ws once and never re-poisons between replays:
    // re-zero the 2048-float accumulator region every call (deterministic).
    zero_ws_kernel<<<(2 * B_ * K_) / 256, 256, 0, stream>>>(ws);
    attn_stats_kernel<<<B_ * CHUNKS_, TPB_, 0, stream>>>(attn, ws);
    finalize_kernel<<<B_ * K_, 64, 0, stream>>>(slots, conf, W1, b1, W2, b2, ws, out);
}

// Round 2
// 60.960 us; speedup vs baseline: 1.1066x; 1.1066x over previous
//
#include <hip/hip_runtime.h>
#include <math.h>

// Problem constants (match reference file)
#define B_ 64
#define K_ 16
#define N_ 65536
#define D_ 256
#define H_ 64

#define N4_ (N_ / 4)          // 16384 float4 columns per (b,k) row
#define CHUNKS_ 32            // blocks per batch element
#define TPB_ 256
#define COLS_ (N4_ / CHUNKS_) // 512 float4-cols per block
#define ITERS_ (COLS_ / TPB_) // 2 iterations per thread

typedef float f32x4 __attribute__((ext_vector_type(4)));

// ws layout: per block (b,chunk): 32 floats = [tot[0..16), win[0..16)]
// 2048 blocks * 32 floats = 256 KiB. Every slot written unconditionally each
// call -> no zeroing needed (harness poisons ws once; we overwrite).

__global__ __launch_bounds__(TPB_) void attn_stats_kernel(const float* __restrict__ attn,
                                                          float* __restrict__ ws) {
    const int b = blockIdx.x / CHUNKS_;
    const int chunk = blockIdx.x % CHUNKS_;
    const f32x4* base = reinterpret_cast<const f32x4*>(attn) + (size_t)b * K_ * N4_;

    float tot[K_], win[K_];
#pragma unroll
    for (int k = 0; k < K_; ++k) { tot[k] = 0.0f; win[k] = 0.0f; }

#pragma unroll
    for (int it = 0; it < ITERS_; ++it) {
        const int c = chunk * COLS_ + it * TPB_ + threadIdx.x;
        // k = 0 initializes the running argmax (winner's value IS the column max)
        f32x4 f = __builtin_nontemporal_load(&base[c]);
        float m0 = f.x, m1 = f.y, m2 = f.z, m3 = f.w;
        int i0 = 0, i1 = 0, i2 = 0, i3 = 0;
        tot[0] += (f.x + f.y) + (f.z + f.w);
#pragma unroll
        for (int k = 1; k < K_; ++k) {
            f = __builtin_nontemporal_load(&base[(size_t)k * N4_ + c]);
            tot[k] += (f.x + f.y) + (f.z + f.w);
            // strict > keeps the FIRST max, matching jnp.argmax tie-break
            if (f.x > m0) { m0 = f.x; i0 = k; }
            if (f.y > m1) { m1 = f.y; i1 = k; }
            if (f.z > m2) { m2 = f.z; i2 = k; }
            if (f.w > m3) { m3 = f.w; i3 = k; }
        }
        // scatter with static indexing (runtime-indexed VGPR arrays spill)
#pragma unroll
        for (int k = 0; k < K_; ++k) {
            win[k] += ((i0 == k) ? m0 : 0.0f) + ((i1 == k) ? m1 : 0.0f) +
                      ((i2 == k) ? m2 : 0.0f) + ((i3 == k) ? m3 : 0.0f);
        }
    }

    // intra-wave butterfly reduction (wave = 64 lanes on CDNA)
#pragma unroll
    for (int k = 0; k < K_; ++k) {
        float t = tot[k], w = win[k];
#pragma unroll
        for (int s = 1; s < 64; s <<= 1) {
            t += __shfl_xor(t, s, 64);
            w += __shfl_xor(w, s, 64);
        }
        tot[k] = t; win[k] = w;
    }

    // cross-wave reduction via LDS, then one coalesced 128 B partial write
    __shared__ float s_tot[4][K_];
    __shared__ float s_win[4][K_];
    const int lane = threadIdx.x & 63;
    const int wv = threadIdx.x >> 6;
    if (lane == 0) {
#pragma unroll
        for (int k = 0; k < K_; ++k) { s_tot[wv][k] = tot[k]; s_win[wv][k] = win[k]; }
    }
    __syncthreads();
    if (threadIdx.x < 2 * K_) {
        const int k = threadIdx.x & (K_ - 1);
        float v;
        if (threadIdx.x < K_) {
            v = (s_tot[0][k] + s_tot[1][k]) + (s_tot[2][k] + s_tot[3][k]);
        } else {
            v = (s_win[0][k] + s_win[1][k]) + (s_win[2][k] + s_win[3][k]);
        }
        ws[(size_t)blockIdx.x * (2 * K_) + threadIdx.x] = v;
    }
}

// One 64-thread block per (b,k): reduce 32 chunk-partials, tiny MLP, combine.
__global__ __launch_bounds__(64) void finalize_kernel(const float* __restrict__ slots,
                                                      const float* __restrict__ conf,
                                                      const float* __restrict__ W1,
                                                      const float* __restrict__ b1,
                                                      const float* __restrict__ W2,
                                                      const float* __restrict__ b2,
                                                      const float* __restrict__ ws,
                                                      float* __restrict__ out) {
    const int bk = blockIdx.x;       // 0 .. B*K-1
    const int b = bk / K_;
    const int k = bk % K_;
    const int j = threadIdx.x;       // 0 .. 63

    __shared__ float s_slot[D_];
    reinterpret_cast<float4*>(s_slot)[j] =
        reinterpret_cast<const float4*>(slots + (size_t)bk * D_)[j];

    // lanes 0-31: tot partial for chunk j; lanes 32-63: win partial for chunk j-32
    const int ch = j & 31;
    float red = (j < 32) ? ws[(size_t)(b * CHUNKS_ + ch) * (2 * K_) + k]
                         : ws[(size_t)(b * CHUNKS_ + ch) * (2 * K_) + K_ + k];
#pragma unroll
    for (int s = 1; s < 32; s <<= 1) red += __shfl_xor(red, s, 64);
    // lane 0 now holds total_attn, lane 32 holds winning_attn

    __syncthreads();

    float acc = b1[j];
#pragma unroll 8
    for (int d = 0; d < D_; ++d) {
        acc = fmaf(s_slot[d], W1[d * H_ + j], acc);   // W1 column read coalesced over j
    }
    const float h = fmaxf(acc, 0.0f);                 // ReLU (dropout = identity at eval)
    float val = h * W2[j];
#pragma unroll
    for (int s = 1; s < 64; s <<= 1) val += __shfl_xor(val, s, 64);

    const float w = __shfl(red, 32, 64);              // winning_attn to all lanes
    if (j == 0) {
        const float t = red;
        const float lq = 1.0f / (1.0f + expf(-(val + b2[0])));   // sigmoid
        const float aq = w / (t + 1e-8f);
        const float q = 0.4f * aq + 0.4f * lq;
        out[bk] = q * 0.2f + conf[bk] * 0.8f;
    }
}

extern "C" void kernel_launch(void* const* d_in, const int* in_sizes, int n_in,
                              void* d_out, int out_size, void* d_ws, size_t ws_size,
                              hipStream_t stream) {
    const float* slots = (const float*)d_in[0];   // [B,K,D]
    const float* attn  = (const float*)d_in[1];   // [B,K,N]
    const float* conf  = (const float*)d_in[2];   // [B,K]
    const float* W1    = (const float*)d_in[3];   // [D,H]
    const float* b1    = (const float*)d_in[4];   // [H]
    const float* W2    = (const float*)d_in[5];   // [H,1]
    const float* b2    = (const float*)d_in[6];   // [1]
    float* out = (float*)d_out;                   // [B,K]
    float* ws  = (float*)d_ws;                    // >= 256 KiB scratch

    attn_stats_kernel<<<B_ * CHUNKS_, TPB_, 0, stream>>>(attn, ws);
    finalize_kernel<<<B_ * K_, 64, 0, stream>>>(slots, conf, W1, b1, W2, b2, ws, out);
}